// Round 1
// 553.565 us; speedup vs baseline: 1.0924x; 1.0924x over previous
//
#include <hip/hip_runtime.h>

#define DM 768
#define DS 16
#define SEQ 2048
#define BATCH 2
#define MROWS (BATCH*SEQ)   // 4096
#define N_UV (2*DM)         // 1536
#define N_BC (DM*DS)        // 12288
#define NGRP (BATCH*DM/4)   // 384 scan wave-groups
#define SUBMAX 64

typedef _Float16 half8 __attribute__((ext_vector_type(8)));
typedef float floatx4 __attribute__((ext_vector_type(4)));
typedef int i32x4 __attribute__((ext_vector_type(4)));
typedef unsigned short us8 __attribute__((ext_vector_type(8)));
typedef signed char c8 __attribute__((ext_vector_type(8)));

static __device__ __forceinline__ unsigned short f2h(float f) {
  _Float16 h = (_Float16)f;
  return __builtin_bit_cast(unsigned short, h);
}
static __device__ __forceinline__ float h2f(unsigned short u) {
  return (float)__builtin_bit_cast(_Float16, u);
}
static __device__ __forceinline__ float softplus_f(float x) {
  return (x > 20.f) ? x : log1pf(__expf(x));
}
// async global->LDS, 16B per lane; LDS dest = l + lane*16 (l wave-uniform)
static __device__ __forceinline__ void async_cp16(const void* g, void* l) {
  __builtin_amdgcn_global_load_lds(
      (const __attribute__((address_space(1))) void*)g,
      (__attribute__((address_space(3))) void*)l, 16, 0, 0);
}
// sum across each 16-lane row via DPP row_ror (pure VALU, no LDS pipe)
static __device__ __forceinline__ float row_reduce16(float v) {
  int x;
  x = __builtin_amdgcn_update_dpp(0, __builtin_bit_cast(int, v), 0x128, 0xf, 0xf, true);
  v += __builtin_bit_cast(float, x);
  x = __builtin_amdgcn_update_dpp(0, __builtin_bit_cast(int, v), 0x124, 0xf, 0xf, true);
  v += __builtin_bit_cast(float, x);
  x = __builtin_amdgcn_update_dpp(0, __builtin_bit_cast(int, v), 0x122, 0xf, 0xf, true);
  v += __builtin_bit_cast(float, x);
  x = __builtin_amdgcn_update_dpp(0, __builtin_bit_cast(int, v), 0x121, 0xf, 0xf, true);
  v += __builtin_bit_cast(float, x);
  return v;
}

// elementwise fp32 -> fp16 ; n divisible by 1024
__global__ void convert_f2h(const float* __restrict__ in,
                            unsigned short* __restrict__ out, int n) {
  int i = (blockIdx.x * blockDim.x + threadIdx.x) * 4;
  if (i >= n) return;
  float4 f = *(const float4*)(in + i);
  ushort4 h;
  h.x = f2h(f.x); h.y = f2h(f.y); h.z = f2h(f.z); h.w = f2h(f.w);
  *(ushort4*)(out + i) = h;
}

// All 5 weight transposes in one launch (z selects). W [768][N] f32 -> WT [N][768] f16.
__global__ void transpose_w5(const float* __restrict__ W0, const float* __restrict__ W1,
                             const float* __restrict__ W2, const float* __restrict__ W3,
                             const float* __restrict__ W4,
                             unsigned short* __restrict__ T0, unsigned short* __restrict__ T1,
                             unsigned short* __restrict__ T2, unsigned short* __restrict__ T3,
                             unsigned short* __restrict__ T4,
                             int N0, int N1, int N2, int N3, int N4) {
  const float* W; unsigned short* WT; int N;
  switch (blockIdx.z) {
    case 0: W = W0; WT = T0; N = N0; break;
    case 1: W = W1; WT = T1; N = N1; break;
    case 2: W = W2; WT = T2; N = N2; break;
    case 3: W = W3; WT = T3; N = N3; break;
    default: W = W4; WT = T4; N = N4; break;
  }
  int n0 = blockIdx.x * 32;
  if (n0 >= N) return;
  int k0 = blockIdx.y * 32;
  __shared__ float tile[32][33];
  int tx = threadIdx.x, ty = threadIdx.y;   // (32,8)
#pragma unroll
  for (int i = 0; i < 32; i += 8)
    tile[ty + i][tx] = W[(size_t)(k0 + ty + i) * N + (n0 + tx)];
  __syncthreads();
  int kp = tx & 15, half = tx >> 4;
#pragma unroll
  for (int i = 0; i < 2; i++) {
    int nl = ty + half * 8 + i * 16;
    unsigned int pk = (unsigned int)f2h(tile[2 * kp][nl]) |
                      ((unsigned int)f2h(tile[2 * kp + 1][nl]) << 16);
    *(unsigned int*)&WT[(size_t)(n0 + nl) * DM + k0 + 2 * kp] = pk;
  }
}

// Per-row symmetric int8 quant: in [R][768] f16 -> out [R][768] i8 + scale[R]
// (scale = rowmax/127). One wave per row; no atomics. blockIdx.y picks matrix.
__global__ __launch_bounds__(256)
void quant_rows(const unsigned short* __restrict__ in0,
                const unsigned short* __restrict__ in1,
                signed char* __restrict__ out0, signed char* __restrict__ out1,
                float* __restrict__ sc0, float* __restrict__ sc1, int R) {
  const unsigned short* in = blockIdx.y ? in1 : in0;
  signed char* out = blockIdx.y ? out1 : out0;
  float* scp = blockIdx.y ? sc1 : sc0;
  int row = blockIdx.x * 4 + (threadIdx.x >> 6);
  if (row >= R) return;
  int lane = threadIdx.x & 63;
  const us8* ch = (const us8*)(in + (size_t)row * DM);   // 96 chunks of 8 halfs
  us8 a = ch[lane];
  us8 b = ch[64 + (lane & 31)];
  float fa[8], fb[8];
  float m = 0.f;
#pragma unroll
  for (int j = 0; j < 8; j++) { fa[j] = h2f(a[j]); m = fmaxf(m, fabsf(fa[j])); }
#pragma unroll
  for (int j = 0; j < 8; j++) fb[j] = h2f(b[j]);
  if (lane < 32) {
#pragma unroll
    for (int j = 0; j < 8; j++) m = fmaxf(m, fabsf(fb[j]));
  }
#pragma unroll
  for (int off = 32; off; off >>= 1) m = fmaxf(m, __shfl_xor(m, off));
  float inv = (m > 0.f) ? 127.f / m : 0.f;
  if (lane == 0) scp[row] = m * (1.f / 127.f);
  c8 qa, qb;
#pragma unroll
  for (int j = 0; j < 8; j++)
    qa[j] = (signed char)__float2int_rn(fminf(fmaxf(fa[j] * inv, -127.f), 127.f));
#pragma unroll
  for (int j = 0; j < 8; j++)
    qb[j] = (signed char)__float2int_rn(fminf(fmaxf(fb[j] * inv, -127.f), 127.f));
  c8* o = (c8*)(out + (size_t)row * DM);
  o[lane] = qa;
  if (lane < 32) o[64 + lane] = qb;
}

// C[M][N] = A[g(M)][K] @ BT[N][K]^T + bias ; ACT=1 -> softplus ; OUTH=1 -> fp16
// A-row remap g(m) = (m/TCa)*bstride + row0 + (m%TCa). gridDim.z picks the
// (BT,bias,out) set. 128x128 tile, BK=32, global_load_lds width-16 staging
// into XOR-swizzled [128][32] LDS (chunk q of row r at q ^ ((r>>1)&3)).
template<int ACT, int OUTH>
__global__ __launch_bounds__(256)
void gemm_f16(const unsigned short* __restrict__ A,
              const unsigned short* __restrict__ BT0,
              const unsigned short* __restrict__ BT1,
              const float* __restrict__ bias0,
              const float* __restrict__ bias1,
              void* __restrict__ Cout0,
              void* __restrict__ Cout1,
              int M, int N, int K, int TCa, int bstride, int row0) {
  const unsigned short* BT = blockIdx.z ? BT1 : BT0;
  const float* bias = blockIdx.z ? bias1 : bias0;
  void* Cout = blockIdx.z ? Cout1 : Cout0;
  __shared__ __align__(16) unsigned short As[128 * 32];
  __shared__ __align__(16) unsigned short Bs[128 * 32];
  const int m0 = blockIdx.y * 128, n0 = blockIdx.x * 128;
  const int tid = threadIdx.x;
  const int lane = tid & 63, wave = tid >> 6;
  const int wm = (wave >> 1) * 64, wn = (wave & 1) * 64;
  const int l16 = lane & 15, quad = lane >> 4;
  const int sr = tid >> 2;                               // staging row 0..63
  const int sc = (((tid & 3) ^ ((tid >> 3) & 3))) * 8;   // swizzled src chunk
  const int pch = (quad ^ ((l16 >> 1) & 3)) * 8;         // swizzled read chunk

  floatx4 acc[4][4] = {};

  const int mA0 = m0 + sr, mA1 = m0 + sr + 64;
  const int gA0 = (mA0 / TCa) * bstride + row0 + (mA0 % TCa);
  const int gA1 = (mA1 / TCa) * bstride + row0 + (mA1 % TCa);
  const unsigned short* Arow0 = A + (size_t)gA0 * K + sc;
  const unsigned short* Arow1 = A + (size_t)gA1 * K + sc;
  const unsigned short* Brow0 = BT + (size_t)(n0 + sr) * K + sc;
  const unsigned short* Brow1 = BT + (size_t)(n0 + sr + 64) * K + sc;
  unsigned short* ldsA0 = As + (wave * 16) * 32;
  unsigned short* ldsA1 = As + (64 + wave * 16) * 32;
  unsigned short* ldsB0 = Bs + (wave * 16) * 32;
  unsigned short* ldsB1 = Bs + (64 + wave * 16) * 32;

  for (int k0 = 0; k0 < K; k0 += 32) {
    async_cp16(Arow0 + k0, ldsA0);
    async_cp16(Arow1 + k0, ldsA1);
    async_cp16(Brow0 + k0, ldsB0);
    async_cp16(Brow1 + k0, ldsB1);
    __syncthreads();
    half8 af[4], bf[4];
#pragma unroll
    for (int i = 0; i < 4; i++) {
      af[i] = __builtin_bit_cast(half8, *(const uint4*)&As[(wm + i * 16 + l16) * 32 + pch]);
      bf[i] = __builtin_bit_cast(half8, *(const uint4*)&Bs[(wn + i * 16 + l16) * 32 + pch]);
    }
#pragma unroll
    for (int mi = 0; mi < 4; mi++)
#pragma unroll
      for (int ni = 0; ni < 4; ni++)
        acc[mi][ni] = __builtin_amdgcn_mfma_f32_16x16x32_f16(af[mi], bf[ni], acc[mi][ni], 0, 0, 0);
    __syncthreads();
  }

  // C/D layout: col = lane&15, row = (lane>>4)*4 + reg
#pragma unroll
  for (int ni = 0; ni < 4; ni++) {
    int col = n0 + wn + ni * 16 + l16;
    float bv = bias[col];
#pragma unroll
    for (int mi = 0; mi < 4; mi++) {
#pragma unroll
      for (int r = 0; r < 4; r++) {
        int row = m0 + wm + mi * 16 + quad * 4 + r;
        float v = acc[mi][ni][r] + bv;
        if (ACT == 1) v = softplus_f(v);
        if (OUTH) ((unsigned short*)Cout)[(size_t)row * N + col] = f2h(v);
        else      ((float*)Cout)[(size_t)row * N + col] = v;
      }
    }
  }
}

// int8 variant for the B/C projection: BK=64 (64B rows in LDS, same XOR
// swizzle at 16B granularity), mfma_i32_16x16x64_i8 (2x f16 rate, half the
// instruction count / staging bytes / barrier drains per unit K).
// Epilogue dequant: C = acc * sA[row]*sB[col] + bias, emitted fp16.
__global__ __launch_bounds__(256)
void gemm_i8(const signed char* __restrict__ A,
             const signed char* __restrict__ BT0,
             const signed char* __restrict__ BT1,
             const float* __restrict__ bias0,
             const float* __restrict__ bias1,
             const float* __restrict__ sA,
             const float* __restrict__ sB0,
             const float* __restrict__ sB1,
             unsigned short* __restrict__ C0,
             unsigned short* __restrict__ C1,
             int M, int N, int K, int TCa, int bstride, int row0) {
  const signed char* BT = blockIdx.z ? BT1 : BT0;
  const float* bias = blockIdx.z ? bias1 : bias0;
  const float* sB = blockIdx.z ? sB1 : sB0;
  unsigned short* Cout = blockIdx.z ? C1 : C0;
  __shared__ __align__(16) signed char As[128 * 64];
  __shared__ __align__(16) signed char Bs[128 * 64];
  const int m0 = blockIdx.y * 128, n0 = blockIdx.x * 128;
  const int tid = threadIdx.x;
  const int lane = tid & 63, wave = tid >> 6;
  const int wm = (wave >> 1) * 64, wn = (wave & 1) * 64;
  const int l16 = lane & 15, quad = lane >> 4;
  const int sr = tid >> 2;                               // staging row 0..63
  const int sc = ((tid & 3) ^ ((tid >> 3) & 3)) * 16;    // swizzled src chunk (bytes)
  const int pch = (quad ^ ((l16 >> 1) & 3)) * 16;        // swizzled read chunk (bytes)

  i32x4 acc[4][4] = {};

  const int mA0 = m0 + sr, mA1 = m0 + sr + 64;
  const int gA0 = (mA0 / TCa) * bstride + row0 + (mA0 % TCa);
  const int gA1 = (mA1 / TCa) * bstride + row0 + (mA1 % TCa);
  const signed char* Arow0 = A + (size_t)gA0 * K + sc;
  const signed char* Arow1 = A + (size_t)gA1 * K + sc;
  const signed char* Brow0 = BT + (size_t)(n0 + sr) * K + sc;
  const signed char* Brow1 = BT + (size_t)(n0 + sr + 64) * K + sc;
  signed char* ldsA0 = As + (wave * 16) * 64;
  signed char* ldsA1 = As + (64 + wave * 16) * 64;
  signed char* ldsB0 = Bs + (wave * 16) * 64;
  signed char* ldsB1 = Bs + (64 + wave * 16) * 64;

  for (int k0 = 0; k0 < K; k0 += 64) {
    async_cp16(Arow0 + k0, ldsA0);
    async_cp16(Arow1 + k0, ldsA1);
    async_cp16(Brow0 + k0, ldsB0);
    async_cp16(Brow1 + k0, ldsB1);
    __syncthreads();
    i32x4 af[4], bf[4];
#pragma unroll
    for (int i = 0; i < 4; i++) {
      af[i] = *(const i32x4*)&As[(wm + i * 16 + l16) * 64 + pch];
      bf[i] = *(const i32x4*)&Bs[(wn + i * 16 + l16) * 64 + pch];
    }
#pragma unroll
    for (int mi = 0; mi < 4; mi++)
#pragma unroll
      for (int ni = 0; ni < 4; ni++)
        acc[mi][ni] = __builtin_amdgcn_mfma_i32_16x16x64_i8(af[mi], bf[ni], acc[mi][ni], 0, 0, 0);
    __syncthreads();
  }

  // g(m) = m + rowAbase within this tile (TCa multiple of 128 => b const)
  const int rowAbase = (m0 / TCa) * (bstride - TCa) + row0;
  float savs[4][4];
#pragma unroll
  for (int mi = 0; mi < 4; mi++)
#pragma unroll
    for (int r = 0; r < 4; r++)
      savs[mi][r] = sA[rowAbase + m0 + wm + mi * 16 + quad * 4 + r];

  // C/D layout: col = lane&15, row = (lane>>4)*4 + reg (dtype-independent)
#pragma unroll
  for (int ni = 0; ni < 4; ni++) {
    int col = n0 + wn + ni * 16 + l16;
    float bv = bias[col];
    float sbv = sB[col];
#pragma unroll
    for (int mi = 0; mi < 4; mi++) {
#pragma unroll
      for (int r = 0; r < 4; r++) {
        int row = m0 + wm + mi * 16 + quad * 4 + r;
        float v = (float)acc[mi][ni][r] * (savs[mi][r] * sbv) + bv;
        Cout[(size_t)row * N + col] = f2h(v);
      }
    }
  }
}

// depthwise causal conv K=4 over u (= uv[:, :768]); 2 channels/thread
__global__ void dwconv(const unsigned short* __restrict__ uv,
                       const float* __restrict__ Wconv,   // [768][4]
                       const float* __restrict__ bconv,
                       unsigned short* __restrict__ uc) {
  int idx = blockIdx.x * 256 + threadIdx.x;   // over MROWS*DM/2
  int c = (idx % (DM / 2)) * 2;
  int row = idx / (DM / 2);
  int t = row & (SEQ - 1);
  float a0 = bconv[c], a1 = bconv[c + 1];
  const float* w0 = Wconv + c * 4;
  const float* w1 = Wconv + (c + 1) * 4;
#pragma unroll
  for (int k = 0; k < 4; k++) {
    int tt = t - 3 + k;
    if (tt >= 0) {
      ushort2 u2 = *(const ushort2*)&uv[(size_t)(row - 3 + k) * N_UV + c];
      a0 += h2f(u2.x) * w0[k];
      a1 += h2f(u2.y) * w1[k];
    }
  }
  ushort2 o; o.x = f2h(a0); o.y = f2h(a1);
  *(ushort2*)&uc[(size_t)row * DM + c] = o;
}

// ---- time-parallel scan over one NC-chunk (row-major streams, R4 structure) ----
// lane = ch*16 + j over 4 channels; grid (NGRP, SUBn); TSUB = TC/SUBn (>=8, %8==0).
__global__ __launch_bounds__(64)
void scan_pass1(const unsigned short* __restrict__ dt,   // fp16 [MROWS][DM]
                const unsigned short* __restrict__ uc,
                const unsigned short* __restrict__ Btc,  // [BATCH*TC][N_BC]
                const float* __restrict__ A_log,
                float* __restrict__ Ssub,                // [SUBn][BATCH][N_BC]
                float* __restrict__ Aexp,
                int ci, int TC, int SUBn) {
  const int TSUB = TC / SUBn;
  int wid = blockIdx.x, sub = blockIdx.y;
  int b = wid / (DM / 4);
  int c0 = (wid % (DM / 4)) * 4;
  int lane = threadIdx.x;
  int c = c0 + (lane >> 4);
  float Acj = -__expf(A_log[c0 * DS + lane]);
  int col = c0 * DS + lane;
  size_t gbase = (size_t)b * SEQ + (size_t)ci * TC + (size_t)sub * TSUB;
  size_t lbase = (size_t)b * TC + (size_t)sub * TSUB;

  float s = 0.f, dsum = 0.f;
  float n_dt[8], n_u[8], n_B[8];
#pragma unroll
  for (int i = 0; i < 8; i++) {
    n_dt[i] = h2f(dt[(gbase + i) * DM + c]);
    n_u[i]  = h2f(uc[(gbase + i) * DM + c]);
    n_B[i]  = h2f(Btc[(lbase + i) * N_BC + col]);
  }
  for (int t0 = 0; t0 < TSUB; t0 += 8) {
    float c_dt[8], c_u[8], c_B[8];
#pragma unroll
    for (int i = 0; i < 8; i++) { c_dt[i] = n_dt[i]; c_u[i] = n_u[i]; c_B[i] = n_B[i]; }
    if (t0 + 8 < TSUB) {
#pragma unroll
      for (int i = 0; i < 8; i++) {
        size_t gr = gbase + t0 + 8 + i, lr = lbase + t0 + 8 + i;
        n_dt[i] = h2f(dt[gr * DM + c]);
        n_u[i]  = h2f(uc[gr * DM + c]);
        n_B[i]  = h2f(Btc[lr * N_BC + col]);
      }
    }
#pragma unroll
    for (int i = 0; i < 8; i++) {
      float dtc = c_dt[i];
      dsum += dtc;
      float a = __expf(dtc * Acj);
      s = fmaf(s, a, dtc * c_B[i] * c_u[i]);
    }
  }
  int idx = (sub * BATCH + b) * N_BC + col;
  Ssub[idx] = s;
  Aexp[idx] = __expf(Acj * dsum);
}

// chain sub-chunk transitions (register-prefetched); Sinit may alias Ssub
// (all loads complete before any store). Carries s_state across NC-chunks.
template<int SUBN>
__global__ __launch_bounds__(64)
void scan_combine(const float* Ssub, const float* Aexp,
                  float* Sinit, float* s_state, int ci) {
  int wid = blockIdx.x;
  int b = wid / (DM / 4);
  int c0 = (wid % (DM / 4)) * 4;
  int col = c0 * DS + threadIdx.x;
  int sidx = b * N_BC + col;
  float sa[SUBN], ae[SUBN];
#pragma unroll
  for (int k = 0; k < SUBN; k++) {
    int idx = (k * BATCH + b) * N_BC + col;
    sa[k] = Ssub[idx];
    ae[k] = Aexp[idx];
  }
  float s = (ci == 0) ? 0.f : s_state[sidx];
#pragma unroll
  for (int k = 0; k < SUBN; k++) {
    int idx = (k * BATCH + b) * N_BC + col;
    Sinit[idx] = s;
    s = fmaf(s, ae[k], sa[k]);
  }
  s_state[sidx] = s;
}

// Pass 2: rerun recurrence from Sinit, emit gated output yg (fp16, row-major)
__global__ __launch_bounds__(64)
void scan_pass2(const unsigned short* __restrict__ dt,
                const unsigned short* __restrict__ uc,
                const unsigned short* __restrict__ Btc,
                const unsigned short* __restrict__ Ctc,
                const unsigned short* __restrict__ uv,
                const float* __restrict__ A_log,
                const float* __restrict__ Dv,
                const float* __restrict__ Sinit,
                unsigned short* __restrict__ yg,
                int ci, int TC, int SUBn) {
  const int TSUB = TC / SUBn;
  int wid = blockIdx.x, sub = blockIdx.y;
  int b = wid / (DM / 4);
  int c0 = (wid % (DM / 4)) * 4;
  int lane = threadIdx.x;
  int j = lane & 15;
  int c = c0 + (lane >> 4);
  float Acj = -__expf(A_log[c0 * DS + lane]);
  float Dc = Dv[c];
  int col = c0 * DS + lane;
  float s = Sinit[(sub * BATCH + b) * N_BC + col];
  size_t gbase = (size_t)b * SEQ + (size_t)ci * TC + (size_t)sub * TSUB;
  size_t lbase = (size_t)b * TC + (size_t)sub * TSUB;

  float n_dt[8], n_u[8], n_B[8], n_C[8], n_v[8];
#pragma unroll
  for (int i = 0; i < 8; i++) {
    size_t gr = gbase + i, lr = lbase + i;
    n_dt[i] = h2f(dt[gr * DM + c]);
    n_u[i]  = h2f(uc[gr * DM + c]);
    n_B[i]  = h2f(Btc[lr * N_BC + col]);
    n_C[i]  = h2f(Ctc[lr * N_BC + col]);
    n_v[i]  = h2f(uv[gr * N_UV + DM + c]);
  }
  for (int t0 = 0; t0 < TSUB; t0 += 8) {
    float c_dt[8], c_u[8], c_B[8], c_C[8], c_v[8];
#pragma unroll
    for (int i = 0; i < 8; i++) {
      c_dt[i] = n_dt[i]; c_u[i] = n_u[i]; c_B[i] = n_B[i];
      c_C[i] = n_C[i]; c_v[i] = n_v[i];
    }
    if (t0 + 8 < TSUB) {
#pragma unroll
      for (int i = 0; i < 8; i++) {
        size_t gr = gbase + t0 + 8 + i, lr = lbase + t0 + 8 + i;
        n_dt[i] = h2f(dt[gr * DM + c]);
        n_u[i]  = h2f(uc[gr * DM + c]);
        n_B[i]  = h2f(Btc[lr * N_BC + col]);
        n_C[i]  = h2f(Ctc[lr * N_BC + col]);
        n_v[i]  = h2f(uv[gr * N_UV + DM + c]);
      }
    }
#pragma unroll
    for (int i = 0; i < 8; i++) {
      float dtc = c_dt[i];
      float a = __expf(dtc * Acj);
      s = fmaf(s, a, dtc * c_B[i] * c_u[i]);
      float yt = row_reduce16(c_C[i] * s);
      if (j == 0) {
        float y = yt + Dc * c_u[i];
        float g = 1.f / (1.f + __expf(-c_v[i]));
        yg[(gbase + t0 + i) * DM + c] = f2h(y * g);
      }
    }
  }
}

extern "C" void kernel_launch(void* const* d_in, const int* in_sizes, int n_in,
                              void* d_out, int out_size, void* d_ws, size_t ws_size,
                              hipStream_t stream) {
  const float* x     = (const float*)d_in[0];
  const float* Wi    = (const float*)d_in[1];
  const float* bi    = (const float*)d_in[2];
  const float* Wconv = (const float*)d_in[3];
  const float* bconv = (const float*)d_in[4];
  const float* Wdt   = (const float*)d_in[5];
  const float* bdt   = (const float*)d_in[6];
  const float* WB    = (const float*)d_in[7];
  const float* bB    = (const float*)d_in[8];
  const float* WC    = (const float*)d_in[9];
  const float* bC    = (const float*)d_in[10];
  const float* A_log = (const float*)d_in[11];
  const float* Dv    = (const float*)d_in[12];
  const float* Wo    = (const float*)d_in[13];
  const float* bo    = (const float*)d_in[14];
  float* out = (float*)d_out;
  (void)in_sizes; (void)n_in; (void)out_size;

  auto pad = [](size_t b) { return (b + 255) & ~(size_t)255; };

  const size_t sz_xb   = pad((size_t)MROWS * DM * 2);      // reused as yg
  const size_t sz_WiT  = pad((size_t)N_UV * DM * 2);
  const size_t sz_WdtT = pad((size_t)DM * DM * 2);
  const size_t sz_WBT  = pad((size_t)N_BC * DM * 2);
  const size_t sz_WCT  = pad((size_t)N_BC * DM * 2);
  const size_t sz_WoT  = pad((size_t)DM * DM * 2);
  const size_t sz_uvb  = pad((size_t)MROWS * N_UV * 2);
  const size_t sz_ucb  = pad((size_t)MROWS * DM * 2);
  const size_t sz_dtb  = pad((size_t)MROWS * DM * 2);
  const size_t sz_st   = pad((size_t)BATCH * N_BC * 4);
  const size_t sz_sub  = pad((size_t)SUBMAX * BATCH * N_BC * 4);  // Ssub(=Sinit)/Aexp
  const size_t sz_uc8  = pad((size_t)MROWS * DM);
  const size_t sz_w8   = pad((size_t)N_BC * DM);
  const size_t sz_sA   = pad((size_t)MROWS * 4);
  const size_t sz_sB   = pad((size_t)N_BC * 4);
  const size_t fixed = sz_xb + sz_WiT + sz_WdtT + sz_WBT + sz_WCT + sz_WoT +
                       sz_uvb + sz_ucb + sz_dtb + sz_st + 2 * sz_sub +
                       sz_uc8 + 2 * sz_w8 + sz_sA + 2 * sz_sB;

  int NC = 16;
  for (int nc : {1, 2, 4, 8, 16}) {
    size_t need = fixed + 2 * pad((size_t)BATCH * (SEQ / nc) * N_BC * 2);
    if (need <= ws_size) { NC = nc; break; }
  }
  const int TC = SEQ / NC;
  const int MC = BATCH * TC;
  const int SUBn = (TC / 8 < SUBMAX) ? (TC / 8) : SUBMAX;   // 64/64/64/32/16

  char* ws = (char*)d_ws;
  size_t off = 0;
  auto alloc = [&](size_t bytes) { char* p = ws + off; off += bytes; return p; };
  unsigned short* xb   = (unsigned short*)alloc(sz_xb);
  unsigned short* WiT  = (unsigned short*)alloc(sz_WiT);
  unsigned short* WdtT = (unsigned short*)alloc(sz_WdtT);
  unsigned short* WBT  = (unsigned short*)alloc(sz_WBT);
  unsigned short* WCT  = (unsigned short*)alloc(sz_WCT);
  unsigned short* WoT  = (unsigned short*)alloc(sz_WoT);
  unsigned short* uvb  = (unsigned short*)alloc(sz_uvb);
  unsigned short* ucb  = (unsigned short*)alloc(sz_ucb);
  unsigned short* dtb  = (unsigned short*)alloc(sz_dtb);
  float*          sst  = (float*)alloc(sz_st);
  float*          Ssub = (float*)alloc(sz_sub);   // aliased as Sinit
  float*          Aexp = (float*)alloc(sz_sub);
  signed char*    uc8  = (signed char*)alloc(sz_uc8);
  signed char*    WBT8 = (signed char*)alloc(sz_w8);
  signed char*    WCT8 = (signed char*)alloc(sz_w8);
  float*          sAu  = (float*)alloc(sz_sA);
  float*          sB0  = (float*)alloc(sz_sB);
  float*          sB1  = (float*)alloc(sz_sB);
  unsigned short* Btc  = (unsigned short*)alloc(pad((size_t)MC * N_BC * 2));
  unsigned short* Ctc  = (unsigned short*)alloc(pad((size_t)MC * N_BC * 2));
  unsigned short* ygb  = xb;   // x fp16 dead after the uv GEMM
  float*          Sini = Ssub; // combine preloads all Ssub before storing Sinit

  convert_f2h<<<dim3(MROWS * DM / 1024), dim3(256), 0, stream>>>(x, xb, MROWS * DM);
  transpose_w5<<<dim3(N_BC / 32, DM / 32, 5), dim3(32, 8), 0, stream>>>(
      Wi, Wdt, WB, WC, Wo, WiT, WdtT, WBT, WCT, WoT, N_UV, DM, N_BC, N_BC, DM);
  // per-row int8 quant of transposed WB/WC (one wave per 768-elem row)
  quant_rows<<<dim3(N_BC / 4, 2), 256, 0, stream>>>(WBT, WCT, WBT8, WCT8,
                                                    sB0, sB1, N_BC);

  // uv = x @ Wi + bi   (fp16, row-major)
  gemm_f16<0, 1><<<dim3(N_UV / 128, MROWS / 128, 1), 256, 0, stream>>>(
      xb, WiT, WiT, bi, bi, uvb, uvb, MROWS, N_UV, DM, MROWS, 0, 0);
  dwconv<<<dim3(MROWS * DM / 512), 256, 0, stream>>>(uvb, Wconv, bconv, ucb);
  // per-row int8 quant of u_conv for the B/C projection
  quant_rows<<<dim3(MROWS / 4, 1), 256, 0, stream>>>(ucb, ucb, uc8, uc8,
                                                     sAu, sAu, MROWS);
  // dt = softplus(u_conv @ Wdt + bdt)  (fp16, row-major)
  gemm_f16<1, 1><<<dim3(DM / 128, MROWS / 128, 1), 256, 0, stream>>>(
      ucb, WdtT, WdtT, bdt, bdt, dtb, dtb, MROWS, DM, DM, MROWS, 0, 0);

  for (int ci = 0; ci < NC; ci++) {
    // Bt and Ct chunk GEMMs fused via gridDim.z (int8 MFMA, fp16 out)
    gemm_i8<<<dim3(N_BC / 128, MC / 128, 2), 256, 0, stream>>>(
        uc8, WBT8, WCT8, bB, bC, sAu, sB0, sB1, Btc, Ctc,
        MC, N_BC, DM, TC, SEQ, ci * TC);
    scan_pass1<<<dim3(NGRP, SUBn), 64, 0, stream>>>(dtb, ucb, Btc, A_log,
                                                    Ssub, Aexp, ci, TC, SUBn);
    switch (SUBn) {
      case 64: scan_combine<64><<<dim3(NGRP), 64, 0, stream>>>(Ssub, Aexp, Sini, sst, ci); break;
      case 32: scan_combine<32><<<dim3(NGRP), 64, 0, stream>>>(Ssub, Aexp, Sini, sst, ci); break;
      default: scan_combine<16><<<dim3(NGRP), 64, 0, stream>>>(Ssub, Aexp, Sini, sst, ci); break;
    }
    scan_pass2<<<dim3(NGRP, SUBn), 64, 0, stream>>>(dtb, ucb, Btc, Ctc, uvb,
                                                    A_log, Dv, Sini, ygb, ci, TC, SUBn);
  }

  // out = yg @ Wo + bo  (fp32, row-major)
  gemm_f16<0, 0><<<dim3(DM / 128, MROWS / 128, 1), 256, 0, stream>>>(
      ygb, WoT, WoT, bo, bo, out, out, MROWS, DM, DM, MROWS, 0, 0);
}